// Round 1
// 591.407 us; speedup vs baseline: 1.0116x; 1.0116x over previous
//
#include <hip/hip_runtime.h>
#include <math.h>

#define IMG_H 1080
#define IMG_W 1920
#define NPIX (IMG_H * IMG_W)

// Tile grid. 64x8 px tiles: 30 x 135 = 4050 tiles, 512 px/tile.
// LDS acc = 512 px * 5 ch * 4B = 10 KB.
#define TILE_W 64
#define TILE_H 8
#define NTX (IMG_W / TILE_W)   // 30
#define NTY (IMG_H / TILE_H)   // 135
#define NTILES (NTX * NTY)     // 4050
#define TPIX (TILE_W * TILE_H) // 512
#define CAP 2048               // slab slots per tile (worst-case est ~900)

// Projection exactly mirroring the reference.
__device__ __forceinline__ void project_pt(
    const float* __restrict__ vm, const float* __restrict__ Km,
    float mx, float my, float mz,
    float& x, float& y, float& z, bool& on)
{
    float mcx = vm[0] * mx + vm[1] * my + vm[2]  * mz + vm[3];
    float mcy = vm[4] * mx + vm[5] * my + vm[6]  * mz + vm[7];
    float mcz = vm[8] * mx + vm[9] * my + vm[10] * mz + vm[11];
    z = mcz;
    bool front = z > 0.1f;
    float z_safe = front ? z : 1.0f;
    float fx = Km[0], fy = Km[4], cx = Km[2], cy = Km[5];
    x = mcx * fx / z_safe + cx;
    y = mcy * fy / z_safe + cy;
    on = front && (x >= 0.0f) && (x < (float)(IMG_W - 1))
               && (y >= 0.0f) && (y < (float)(IMG_H - 1));
}

// Pass 1: scatter-min of z into zbuf at (y0,x0).
__global__ __launch_bounds__(256) void k_zmin(
    const float* __restrict__ means, const float* __restrict__ vm,
    const float* __restrict__ Km, unsigned int* __restrict__ zbuf, int N)
{
    int i = blockIdx.x * 256 + threadIdx.x;
    if (i >= N) return;
    float x, y, z; bool on;
    project_pt(vm, Km, means[3 * i], means[3 * i + 1], means[3 * i + 2], x, y, z, on);
    if (!on) return;
    int x0 = (int)floorf(x), y0 = (int)floorf(y);
    atomicMin(&zbuf[y0 * IMG_W + x0], __float_as_uint(z));
}

// ---------------- PRIMARY PATH: payload records (float4, 16 B) ----------------
// Record = {x, y, z, rgb packed 10:10:10}. k_tile streams its slab coalesced
// and never gathers means/colors (kills the 198 MB scattered FETCH).

__global__ __launch_bounds__(256) void k_scatter_f4(
    const float* __restrict__ means, const float* __restrict__ colors,
    const float* __restrict__ vm, const float* __restrict__ Km,
    const unsigned int* __restrict__ zbuf,
    unsigned int* __restrict__ cursors, float4* __restrict__ records, int N)
{
    int i = blockIdx.x * 256 + threadIdx.x;
    if (i >= N) return;
    float x, y, z; bool on;
    project_pt(vm, Km, means[3 * i], means[3 * i + 1], means[3 * i + 2], x, y, z, on);
    if (!on) return;
    int x0 = (int)floorf(x), y0 = (int)floorf(y);
    int pix = y0 * IMG_W + x0;
    if (!(z <= __uint_as_float(zbuf[pix]) + 0.05f)) return;   // vis cull
    float r = 1.0f / (1.0f + expf(-colors[3 * i]));
    float g = 1.0f / (1.0f + expf(-colors[3 * i + 1]));
    float b = 1.0f / (1.0f + expf(-colors[3 * i + 2]));
    // sigmoid output in (0,1) -> 10-bit fits without clamping (err <= 4.9e-4)
    unsigned int ri = (unsigned int)(r * 1023.0f + 0.5f);
    unsigned int gi = (unsigned int)(g * 1023.0f + 0.5f);
    unsigned int bi = (unsigned int)(b * 1023.0f + 0.5f);
    float4 rec = make_float4(x, y, z, __uint_as_float(ri | (gi << 10) | (bi << 20)));
    int tx0 = x0 / TILE_W, ty0 = y0 / TILE_H;
    int tx1 = (x0 + 1) / TILE_W, ty1 = (y0 + 1) / TILE_H;
#pragma unroll
    for (int sy = 0; sy < 2; ++sy) {
        int ty = sy ? ty1 : ty0;
        if (sy && ty1 == ty0) continue;
#pragma unroll
        for (int sx = 0; sx < 2; ++sx) {
            int tx = sx ? tx1 : tx0;
            if (sx && tx1 == tx0) continue;
            int t = ty * NTX + tx;
            unsigned int slot = atomicAdd(&cursors[t], 1u);
            if (slot < CAP) records[(size_t)t * CAP + slot] = rec;
        }
    }
}

__global__ __launch_bounds__(256) void k_tile_f4(
    const unsigned int* __restrict__ cursors,
    const float4* __restrict__ records, float* __restrict__ out)
{
    __shared__ float sR[TPIX], sG[TPIX], sB[TPIX], sZ[TPIX], sW[TPIX];
    int tid = threadIdx.x;
    int t = blockIdx.x;
    int txb = (t % NTX) * TILE_W;
    int tyb = (t / NTX) * TILE_H;
    for (int p = tid; p < TPIX; p += 256) {
        sR[p] = 0.0f; sG[p] = 0.0f; sB[p] = 0.0f; sZ[p] = 0.0f; sW[p] = 0.0f;
    }
    __syncthreads();

    int cnt = (int)min(cursors[t], (unsigned int)CAP);
    const float4* rec = records + (size_t)t * CAP;
    for (int j = tid; j < cnt; j += 256) {
        float4 v = rec[j];                 // coalesced 16 B stream
        float x = v.x, y = v.y, z = v.z;
        unsigned int rgb = __float_as_uint(v.w);
        float r = (float)(rgb & 1023u) * (1.0f / 1023.0f);
        float g = (float)((rgb >> 10) & 1023u) * (1.0f / 1023.0f);
        float b = (float)((rgb >> 20) & 1023u) * (1.0f / 1023.0f);
        float x0f = floorf(x), y0f = floorf(y);
        int x0 = (int)x0f, y0 = (int)y0f;
        float dx = x - x0f, dy = y - y0f;
        float wa = (1.0f - dx) * (1.0f - dy);
        float wb = dx * (1.0f - dy);
        float wc = (1.0f - dx) * dy;
        float wd = dx * dy;
        int cxs[4] = { x0, x0, x0 + 1, x0 + 1 };
        int cys[4] = { y0, y0 + 1, y0, y0 + 1 };
        float ws[4] = { wa, wb, wc, wd };
#pragma unroll
        for (int c = 0; c < 4; ++c) {
            int lx = cxs[c] - txb, ly = cys[c] - tyb;
            if ((unsigned)lx < TILE_W && (unsigned)ly < TILE_H) {
                int lp = ly * TILE_W + lx;
                float w = ws[c];
                atomicAdd(&sR[lp], r * w);
                atomicAdd(&sG[lp], g * w);
                atomicAdd(&sB[lp], b * w);
                atomicAdd(&sZ[lp], z * w);
                atomicAdd(&sW[lp], w);
            }
        }
    }
    __syncthreads();

    for (int p = tid; p < TPIX; p += 256) {
        float tot = sW[p] + 1e-6f;
        float r = sR[p] / tot, g = sG[p] / tot, b = sB[p] / tot, zz = sZ[p] / tot;
        r = fminf(fmaxf(r, 0.0f), 1.0f);
        g = fminf(fmaxf(g, 0.0f), 1.0f);
        b = fminf(fmaxf(b, 0.0f), 1.0f);
        int gy = tyb + p / TILE_W, gx = txb + p % TILE_W;
        reinterpret_cast<float4*>(out)[gy * IMG_W + gx] = make_float4(r, g, b, zz);
    }
}

// ---------------- TIER 2: packed 8-B payload records (uint2) ----------------
// Tile-local position at 1/256 px (err 2e-3 px), z 16-bit/4096 (err 1.2e-4),
// rgb 7-bit (err 3.9e-3) -- all far under the 0.03 tolerance scale.
// word0: xq[0:15) | yq[15:27) | zq.lo5[27:32)
// word1: zq.hi11[0:11) | r7[11:18) | g7[18:25) | b7[25:32)

__global__ __launch_bounds__(256) void k_scatter_p8(
    const float* __restrict__ means, const float* __restrict__ colors,
    const float* __restrict__ vm, const float* __restrict__ Km,
    const unsigned int* __restrict__ zbuf,
    unsigned int* __restrict__ cursors, uint2* __restrict__ records, int N)
{
    int i = blockIdx.x * 256 + threadIdx.x;
    if (i >= N) return;
    float x, y, z; bool on;
    project_pt(vm, Km, means[3 * i], means[3 * i + 1], means[3 * i + 2], x, y, z, on);
    if (!on) return;
    int x0 = (int)floorf(x), y0 = (int)floorf(y);
    int pix = y0 * IMG_W + x0;
    if (!(z <= __uint_as_float(zbuf[pix]) + 0.05f)) return;
    float r = 1.0f / (1.0f + expf(-colors[3 * i]));
    float g = 1.0f / (1.0f + expf(-colors[3 * i + 1]));
    float b = 1.0f / (1.0f + expf(-colors[3 * i + 2]));
    unsigned int rq = (unsigned int)(r * 127.0f + 0.5f);
    unsigned int gq = (unsigned int)(g * 127.0f + 0.5f);
    unsigned int bq = (unsigned int)(b * 127.0f + 0.5f);
    unsigned int zq = (unsigned int)fminf(z * 4096.0f + 0.5f, 65535.0f);
    unsigned int w1 = (zq >> 5) | (rq << 11) | (gq << 18) | (bq << 25);
    int tx0 = x0 / TILE_W, ty0 = y0 / TILE_H;
    int tx1 = (x0 + 1) / TILE_W, ty1 = (y0 + 1) / TILE_H;
#pragma unroll
    for (int sy = 0; sy < 2; ++sy) {
        int ty = sy ? ty1 : ty0;
        if (sy && ty1 == ty0) continue;
#pragma unroll
        for (int sx = 0; sx < 2; ++sx) {
            int tx = sx ? tx1 : tx0;
            if (sx && tx1 == tx0) continue;
            // tile-local coords, offset +1 so range is non-negative
            float xl = x - (float)(tx * TILE_W) + 1.0f;   // [0, 65)
            float yl = y - (float)(ty * TILE_H) + 1.0f;   // [0, 9)
            unsigned int xq = (unsigned int)(xl * 256.0f + 0.5f);  // <= 16640, 15 bits
            unsigned int yq = (unsigned int)(yl * 256.0f + 0.5f);  // <= 2304, 12 bits
            uint2 rec;
            rec.x = xq | (yq << 15) | ((zq & 31u) << 27);
            rec.y = w1;
            int t = ty * NTX + tx;
            unsigned int slot = atomicAdd(&cursors[t], 1u);
            if (slot < CAP) records[(size_t)t * CAP + slot] = rec;
        }
    }
}

__global__ __launch_bounds__(256) void k_tile_p8(
    const unsigned int* __restrict__ cursors,
    const uint2* __restrict__ records, float* __restrict__ out)
{
    __shared__ float sR[TPIX], sG[TPIX], sB[TPIX], sZ[TPIX], sW[TPIX];
    int tid = threadIdx.x;
    int t = blockIdx.x;
    int txb = (t % NTX) * TILE_W;
    int tyb = (t / NTX) * TILE_H;
    for (int p = tid; p < TPIX; p += 256) {
        sR[p] = 0.0f; sG[p] = 0.0f; sB[p] = 0.0f; sZ[p] = 0.0f; sW[p] = 0.0f;
    }
    __syncthreads();

    int cnt = (int)min(cursors[t], (unsigned int)CAP);
    const uint2* rec = records + (size_t)t * CAP;
    for (int j = tid; j < cnt; j += 256) {
        uint2 v = rec[j];
        unsigned int w0 = v.x, w1 = v.y;
        float xl = (float)(w0 & 0x7FFFu) * (1.0f / 256.0f) - 1.0f;        // x - txb
        float yl = (float)((w0 >> 15) & 0xFFFu) * (1.0f / 256.0f) - 1.0f; // y - tyb
        unsigned int zq = ((w0 >> 27) & 31u) | ((w1 & 0x7FFu) << 5);
        float z = (float)zq * (1.0f / 4096.0f);
        float r = (float)((w1 >> 11) & 127u) * (1.0f / 127.0f);
        float g = (float)((w1 >> 18) & 127u) * (1.0f / 127.0f);
        float b = (float)((w1 >> 25) & 127u) * (1.0f / 127.0f);
        float x0f = floorf(xl), y0f = floorf(yl);
        int lx0 = (int)x0f, ly0 = (int)y0f;   // already tile-local
        float dx = xl - x0f, dy = yl - y0f;
        float wa = (1.0f - dx) * (1.0f - dy);
        float wb = dx * (1.0f - dy);
        float wc = (1.0f - dx) * dy;
        float wd = dx * dy;
        int cxs[4] = { lx0, lx0, lx0 + 1, lx0 + 1 };
        int cys[4] = { ly0, ly0 + 1, ly0, ly0 + 1 };
        float ws[4] = { wa, wb, wc, wd };
#pragma unroll
        for (int c = 0; c < 4; ++c) {
            int lx = cxs[c], ly = cys[c];
            if ((unsigned)lx < TILE_W && (unsigned)ly < TILE_H) {
                int lp = ly * TILE_W + lx;
                float w = ws[c];
                atomicAdd(&sR[lp], r * w);
                atomicAdd(&sG[lp], g * w);
                atomicAdd(&sB[lp], b * w);
                atomicAdd(&sZ[lp], z * w);
                atomicAdd(&sW[lp], w);
            }
        }
    }
    __syncthreads();

    for (int p = tid; p < TPIX; p += 256) {
        float tot = sW[p] + 1e-6f;
        float r = sR[p] / tot, g = sG[p] / tot, b = sB[p] / tot, zz = sZ[p] / tot;
        r = fminf(fmaxf(r, 0.0f), 1.0f);
        g = fminf(fmaxf(g, 0.0f), 1.0f);
        b = fminf(fmaxf(b, 0.0f), 1.0f);
        int gy = tyb + p / TILE_W, gx = txb + p % TILE_W;
        reinterpret_cast<float4*>(out)[gy * IMG_W + gx] = make_float4(r, g, b, zz);
    }
}

// ---------------- TIER 3: proven u32-index path (41.5 MB ws) ----------------

__global__ __launch_bounds__(256) void k_scatter_u32(
    const float* __restrict__ means, const float* __restrict__ vm,
    const float* __restrict__ Km, const unsigned int* __restrict__ zbuf,
    unsigned int* __restrict__ cursors, unsigned int* __restrict__ records, int N)
{
    int i = blockIdx.x * 256 + threadIdx.x;
    if (i >= N) return;
    float x, y, z; bool on;
    project_pt(vm, Km, means[3 * i], means[3 * i + 1], means[3 * i + 2], x, y, z, on);
    if (!on) return;
    int x0 = (int)floorf(x), y0 = (int)floorf(y);
    int pix = y0 * IMG_W + x0;
    if (!(z <= __uint_as_float(zbuf[pix]) + 0.05f)) return;
    int tx0 = x0 / TILE_W, ty0 = y0 / TILE_H;
    int tx1 = (x0 + 1) / TILE_W, ty1 = (y0 + 1) / TILE_H;
#pragma unroll
    for (int sy = 0; sy < 2; ++sy) {
        int ty = sy ? ty1 : ty0;
        if (sy && ty1 == ty0) continue;
#pragma unroll
        for (int sx = 0; sx < 2; ++sx) {
            int tx = sx ? tx1 : tx0;
            if (sx && tx1 == tx0) continue;
            int t = ty * NTX + tx;
            unsigned int slot = atomicAdd(&cursors[t], 1u);
            if (slot < CAP) records[(size_t)t * CAP + slot] = (unsigned int)i;
        }
    }
}

__global__ __launch_bounds__(256) void k_tile_u32(
    const float* __restrict__ means, const float* __restrict__ colors,
    const float* __restrict__ vm, const float* __restrict__ Km,
    const unsigned int* __restrict__ cursors,
    const unsigned int* __restrict__ records,
    float* __restrict__ out)
{
    __shared__ float sR[TPIX], sG[TPIX], sB[TPIX], sZ[TPIX], sW[TPIX];
    int tid = threadIdx.x;
    int t = blockIdx.x;
    int txb = (t % NTX) * TILE_W;
    int tyb = (t / NTX) * TILE_H;
    for (int p = tid; p < TPIX; p += 256) {
        sR[p] = 0.0f; sG[p] = 0.0f; sB[p] = 0.0f; sZ[p] = 0.0f; sW[p] = 0.0f;
    }
    __syncthreads();

    int cnt = (int)min(cursors[t], (unsigned int)CAP);
    const unsigned int* rec = records + (size_t)t * CAP;
    for (int j = tid; j < cnt; j += 256) {
        int i = (int)rec[j];
        float x, y, z; bool on;
        project_pt(vm, Km, means[3 * i], means[3 * i + 1], means[3 * i + 2], x, y, z, on);
        float x0f = floorf(x), y0f = floorf(y);
        int x0 = (int)x0f, y0 = (int)y0f;
        float dx = x - x0f, dy = y - y0f;
        float wa = (1.0f - dx) * (1.0f - dy);
        float wb = dx * (1.0f - dy);
        float wc = (1.0f - dx) * dy;
        float wd = dx * dy;
        float r = 1.0f / (1.0f + expf(-colors[3 * i]));
        float g = 1.0f / (1.0f + expf(-colors[3 * i + 1]));
        float b = 1.0f / (1.0f + expf(-colors[3 * i + 2]));
        int cxs[4] = { x0, x0, x0 + 1, x0 + 1 };
        int cys[4] = { y0, y0 + 1, y0, y0 + 1 };
        float ws[4] = { wa, wb, wc, wd };
#pragma unroll
        for (int c = 0; c < 4; ++c) {
            int lx = cxs[c] - txb, ly = cys[c] - tyb;
            if ((unsigned)lx < TILE_W && (unsigned)ly < TILE_H) {
                int lp = ly * TILE_W + lx;
                float w = ws[c];
                atomicAdd(&sR[lp], r * w);
                atomicAdd(&sG[lp], g * w);
                atomicAdd(&sB[lp], b * w);
                atomicAdd(&sZ[lp], z * w);
                atomicAdd(&sW[lp], w);
            }
        }
    }
    __syncthreads();

    for (int p = tid; p < TPIX; p += 256) {
        float tot = sW[p] + 1e-6f;
        float r = sR[p] / tot, g = sG[p] / tot, b = sB[p] / tot, zz = sZ[p] / tot;
        r = fminf(fmaxf(r, 0.0f), 1.0f);
        g = fminf(fmaxf(g, 0.0f), 1.0f);
        b = fminf(fmaxf(b, 0.0f), 1.0f);
        int gy = tyb + p / TILE_W, gx = txb + p % TILE_W;
        reinterpret_cast<float4*>(out)[gy * IMG_W + gx] = make_float4(r, g, b, zz);
    }
}

// ---------------- TIER 4: global-atomic fallback (16.6 MB ws) ----------------

__global__ __launch_bounds__(256) void k_splat(
    const float* __restrict__ means, const float* __restrict__ colors,
    const float* __restrict__ vm, const float* __restrict__ Km,
    const float* __restrict__ zbuf,
    float* __restrict__ acc, float* __restrict__ wsum, int N)
{
    int i = blockIdx.x * 256 + threadIdx.x;
    if (i >= N) return;
    float x, y, z; bool on;
    project_pt(vm, Km, means[3 * i], means[3 * i + 1], means[3 * i + 2], x, y, z, on);
    if (!on) return;
    float x0f = floorf(x), y0f = floorf(y);
    int x0 = (int)x0f, y0 = (int)y0f;
    int pix = y0 * IMG_W + x0;
    if (!(z <= zbuf[pix] + 0.05f)) return;
    float dx = x - x0f, dy = y - y0f;
    float wa = (1.0f - dx) * (1.0f - dy);
    float wb = dx * (1.0f - dy);
    float wc = (1.0f - dx) * dy;
    float wd = dx * dy;
    float r = 1.0f / (1.0f + expf(-colors[3 * i]));
    float g = 1.0f / (1.0f + expf(-colors[3 * i + 1]));
    float b = 1.0f / (1.0f + expf(-colors[3 * i + 2]));
    int ia = pix, ib = pix + IMG_W, ic = pix + 1, id = pix + IMG_W + 1;
#define SPLAT1(idx, w)                                    \
    do {                                                  \
        atomicAdd(&acc[4 * (idx) + 0], r * (w));          \
        atomicAdd(&acc[4 * (idx) + 1], g * (w));          \
        atomicAdd(&acc[4 * (idx) + 2], b * (w));          \
        atomicAdd(&acc[4 * (idx) + 3], z * (w));          \
        atomicAdd(&wsum[(idx)], (w));                     \
    } while (0)
    SPLAT1(ia, wa); SPLAT1(ib, wb); SPLAT1(ic, wc); SPLAT1(id, wd);
#undef SPLAT1
}

__global__ __launch_bounds__(256) void k_final(
    float* __restrict__ out, const float* __restrict__ wsum)
{
    int p = blockIdx.x * 256 + threadIdx.x;
    if (p >= NPIX) return;
    float tot = wsum[p] + 1e-6f;
    float4 v = reinterpret_cast<float4*>(out)[p];
    float r = v.x / tot, g = v.y / tot, b = v.z / tot, zz = v.w / tot;
    r = fminf(fmaxf(r, 0.0f), 1.0f);
    g = fminf(fmaxf(g, 0.0f), 1.0f);
    b = fminf(fmaxf(b, 0.0f), 1.0f);
    reinterpret_cast<float4*>(out)[p] = make_float4(r, g, b, zz);
}

extern "C" void kernel_launch(void* const* d_in, const int* in_sizes, int n_in,
                              void* d_out, int out_size, void* d_ws, size_t ws_size,
                              hipStream_t stream)
{
    const float* means  = (const float*)d_in[0];
    const float* colors = (const float*)d_in[1];
    const float* vm     = (const float*)d_in[5];   // viewmat 4x4 row-major
    const float* Km     = (const float*)d_in[6];   // K 3x3 row-major
    int N = in_sizes[0] / 3;
    float* out = (float*)d_out;
    int nb = (N + 255) / 256;

    const size_t zbufB  = (size_t)NPIX * 4;
    const size_t curB   = (size_t)NTILES * 4;
    const size_t recF4B = (size_t)NTILES * CAP * 16;   // ~132.7 MB
    const size_t recP8B = (size_t)NTILES * CAP * 8;    // ~66.4 MB
    const size_t recU4B = (size_t)NTILES * CAP * 4;    // ~33.2 MB

    if (ws_size >= zbufB + curB + recF4B) {
        // ---- primary: 16-B payload records, streaming k_tile
        unsigned int* zbuf    = (unsigned int*)d_ws;
        unsigned int* cursors = (unsigned int*)((char*)d_ws + zbufB);
        float4*       records = (float4*)((char*)d_ws + zbufB + curB);
        hipMemsetAsync(zbuf, 0x7f, zbufB, stream);   // 3.39e38 acts as +inf
        hipMemsetAsync(cursors, 0, curB, stream);
        k_zmin      <<<nb, 256, 0, stream>>>(means, vm, Km, zbuf, N);
        k_scatter_f4<<<nb, 256, 0, stream>>>(means, colors, vm, Km, zbuf,
                                             cursors, records, N);
        k_tile_f4   <<<NTILES, 256, 0, stream>>>(cursors, records, out);
    } else if (ws_size >= zbufB + curB + recP8B) {
        // ---- tier 2: 8-B quantized payload records
        unsigned int* zbuf    = (unsigned int*)d_ws;
        unsigned int* cursors = (unsigned int*)((char*)d_ws + zbufB);
        uint2*        records = (uint2*)((char*)d_ws + zbufB + curB);
        hipMemsetAsync(zbuf, 0x7f, zbufB, stream);
        hipMemsetAsync(cursors, 0, curB, stream);
        k_zmin      <<<nb, 256, 0, stream>>>(means, vm, Km, zbuf, N);
        k_scatter_p8<<<nb, 256, 0, stream>>>(means, colors, vm, Km, zbuf,
                                             cursors, records, N);
        k_tile_p8   <<<NTILES, 256, 0, stream>>>(cursors, records, out);
    } else if (ws_size >= zbufB + curB + recU4B) {
        // ---- tier 3: proven u32-index path (previous session, 596 us)
        unsigned int* zbuf    = (unsigned int*)d_ws;
        unsigned int* cursors = (unsigned int*)((char*)d_ws + zbufB);
        unsigned int* records = (unsigned int*)((char*)d_ws + zbufB + curB);
        hipMemsetAsync(zbuf, 0x7f, zbufB, stream);
        hipMemsetAsync(cursors, 0, curB, stream);
        k_zmin       <<<nb, 256, 0, stream>>>(means, vm, Km, zbuf, N);
        k_scatter_u32<<<nb, 256, 0, stream>>>(means, vm, Km, zbuf, cursors,
                                              records, N);
        k_tile_u32   <<<NTILES, 256, 0, stream>>>(means, colors, vm, Km,
                                                  cursors, records, out);
    } else {
        // ---- tier 4: global-atomic pipeline (16.6 MB ws)
        unsigned int* zbuf = (unsigned int*)d_ws;
        float*        wsum = (float*)((char*)d_ws + zbufB);
        hipMemsetAsync(zbuf, 0x7f, zbufB, stream);
        hipMemsetAsync(wsum, 0x00, zbufB, stream);
        hipMemsetAsync(out,  0x00, (size_t)NPIX * 16, stream);
        k_zmin <<<nb, 256, 0, stream>>>(means, vm, Km, zbuf, N);
        k_splat<<<nb, 256, 0, stream>>>(means, colors, vm, Km,
                                        (const float*)zbuf, out, wsum, N);
        k_final<<<(NPIX + 255) / 256, 256, 0, stream>>>(out, wsum);
    }
}